// Round 9
// baseline (731.867 us; speedup 1.0000x reference)
//
#include <hip/hip_runtime.h>

#define NODES 100000
#define EDGES 1600000
#define CHUNK 8192
#define NCH 196          // ceil(EDGES / CHUNK)
#define BSH 9            // bucket = dst >> 9  (512 nodes per bucket)
#define NBUCK 196        // ceil(NODES / 512)
#define NGRP (NODES / 4) // node groups of 4 (one per wave)

typedef unsigned int uint;
typedef unsigned short ushort;

__device__ __forceinline__ float bf2f(uint u) {
    union { uint i; float f; } c; c.i = u << 16; return c.f;
}
__device__ __forceinline__ ushort f2bf(float f) {
    union { float f; uint i; } c; c.f = f;
    uint r = c.i + 0x7fff + ((c.i >> 16) & 1);   // round-to-nearest-even
    return (ushort)(r >> 16);
}

// ---------------- preprocessing: LDS-binned counting sort by dst ----------------

__global__ __launch_bounds__(256) void k_hist(const int* __restrict__ dst,
                                              int* __restrict__ hist) {
    __shared__ int h[NBUCK];
    const int t = threadIdx.x;
    if (t < NBUCK) h[t] = 0;
    __syncthreads();
    const int base = blockIdx.x * CHUNK;
    const int len = min(CHUNK, EDGES - base);
    for (int i = t; i < len; i += 256)
        atomicAdd(&h[dst[base + i] >> BSH], 1);
    __syncthreads();
    if (t < NBUCK) hist[blockIdx.x * NBUCK + t] = h[t];
}

__global__ void k_offsets(int* __restrict__ hist, int* __restrict__ bucketStart,
                          int* __restrict__ rowptr) {
    __shared__ int tot[NBUCK];
    __shared__ int bstart[NBUCK + 1];
    const int t = threadIdx.x;   // 256 threads
    if (t < NBUCK) {
        int run = 0;
        for (int blk = 0; blk < NCH; ++blk) {
            int c = hist[blk * NBUCK + t];
            hist[blk * NBUCK + t] = run;   // per-bucket local prefix
            run += c;
        }
        tot[t] = run;
    }
    __syncthreads();
    if (t == 0) {
        int acc = 0;
        for (int b = 0; b < NBUCK; ++b) { bstart[b] = acc; acc += tot[b]; }
        bstart[NBUCK] = acc;               // == EDGES
        rowptr[NODES] = acc;
    }
    __syncthreads();
    if (t < NBUCK) {
        int bs = bstart[t];
        for (int blk = 0; blk < NCH; ++blk)
            hist[blk * NBUCK + t] += bs;
    }
    if (t <= NBUCK) bucketStart[t] = bstart[t];
}

__global__ __launch_bounds__(256) void k_bin(const int* __restrict__ src,
                                             const int* __restrict__ dst,
                                             const int* __restrict__ hist,
                                             uint* __restrict__ binned) {
    __shared__ int curs[NBUCK];
    const int t = threadIdx.x;
    if (t < NBUCK) curs[t] = hist[blockIdx.x * NBUCK + t];
    __syncthreads();
    const int base = blockIdx.x * CHUNK;
    const int len = min(CHUNK, EDGES - base);
    for (int i = t; i < len; i += 256) {
        int d = dst[base + i];
        int s = src[base + i];
        int pos = atomicAdd(&curs[d >> BSH], 1);
        binned[pos] = ((uint)(d & 511) << 17) | (uint)s;
    }
}

__global__ __launch_bounds__(256) void k_build(const uint* __restrict__ binned,
                                               const int* __restrict__ bucketStart,
                                               int* __restrict__ rowptr,
                                               float* __restrict__ dis,
                                               int* __restrict__ ssrc) {
    __shared__ int cnt[512];
    __shared__ int sh[256];
    const int t = threadIdx.x;
    const int b = blockIdx.x;
    const int eBase = bucketStart[b], eEnd = bucketStart[b + 1];
    const int nodeBase = b << BSH;
    const int nnode = min(512, NODES - nodeBase);
    cnt[t * 2] = 0; cnt[t * 2 + 1] = 0;
    __syncthreads();
    for (int i = eBase + t; i < eEnd; i += 256)
        atomicAdd(&cnt[binned[i] >> 17], 1);
    __syncthreads();
    const int c0 = cnt[t * 2], c1 = cnt[t * 2 + 1];
    const int sum = c0 + c1;
    sh[t] = sum; __syncthreads();
    for (int off = 1; off < 256; off <<= 1) {
        int add = (t >= off) ? sh[t - off] : 0;
        __syncthreads(); sh[t] += add; __syncthreads();
    }
    int excl = sh[t] - sum;
    const int ln0 = t * 2;
    if (ln0 < nnode) {
        rowptr[nodeBase + ln0] = eBase + excl;
        dis[nodeBase + ln0] = rsqrtf((float)(1 + c0));
    }
    int excl1 = excl + c0;
    if (ln0 + 1 < nnode) {
        rowptr[nodeBase + ln0 + 1] = eBase + excl1;
        dis[nodeBase + ln0 + 1] = rsqrtf((float)(1 + c1));
    }
    cnt[ln0] = excl; cnt[ln0 + 1] = excl1;
    __syncthreads();
    for (int i = eBase + t; i < eEnd; i += 256) {
        uint p = binned[i];
        int pos = atomicAdd(&cnt[p >> 17], 1);
        ssrc[eBase + pos] = (int)(p & 0x1FFFFu);
    }
}

// ---------------- GEMMs: W staged in LDS, dis-scaled bf16 outputs ----------------

// hb'[row] = bf16( dis[row] * (x @ W1)[row] )  (32 rows/block, thread = 4r x 4c)
__global__ __launch_bounds__(256) void k_gemm1(const float* __restrict__ x,
                                               const float* __restrict__ W1,
                                               const float* __restrict__ dis,
                                               ushort* __restrict__ hb) {
    __shared__ float wsh[128 * 128];   // 64 KB
    __shared__ float xs[32 * 128];     // 16 KB
    const int t = threadIdx.x;
    {
        const float4* Wv = (const float4*)W1;
        float4* Sv = (float4*)wsh;
#pragma unroll
        for (int i = 0; i < 16; ++i) Sv[i * 256 + t] = Wv[i * 256 + t];
    }
    const int row0 = blockIdx.x * 32;
    {
        const float4* Xv = (const float4*)(x + (size_t)row0 * 128);
        float4* Sv = (float4*)xs;
#pragma unroll
        for (int i = 0; i < 4; ++i) Sv[i * 256 + t] = Xv[i * 256 + t];
    }
    __syncthreads();
    const int c4 = (t & 31) * 4;
    const int r0 = (t >> 5) * 4;
    float4 a0{0,0,0,0}, a1{0,0,0,0}, a2{0,0,0,0}, a3{0,0,0,0};
#pragma unroll 4
    for (int k = 0; k < 128; ++k) {
        float4 w = *(const float4*)&wsh[k * 128 + c4];
        float x0 = xs[(r0 + 0) * 128 + k];
        float x1 = xs[(r0 + 1) * 128 + k];
        float x2 = xs[(r0 + 2) * 128 + k];
        float x3 = xs[(r0 + 3) * 128 + k];
        a0.x = fmaf(x0, w.x, a0.x); a0.y = fmaf(x0, w.y, a0.y);
        a0.z = fmaf(x0, w.z, a0.z); a0.w = fmaf(x0, w.w, a0.w);
        a1.x = fmaf(x1, w.x, a1.x); a1.y = fmaf(x1, w.y, a1.y);
        a1.z = fmaf(x1, w.z, a1.z); a1.w = fmaf(x1, w.w, a1.w);
        a2.x = fmaf(x2, w.x, a2.x); a2.y = fmaf(x2, w.y, a2.y);
        a2.z = fmaf(x2, w.z, a2.z); a2.w = fmaf(x2, w.w, a2.w);
        a3.x = fmaf(x3, w.x, a3.x); a3.y = fmaf(x3, w.y, a3.y);
        a3.z = fmaf(x3, w.z, a3.z); a3.w = fmaf(x3, w.w, a3.w);
    }
    const float d0 = dis[row0 + r0], d1 = dis[row0 + r0 + 1];
    const float d2 = dis[row0 + r0 + 2], d3 = dis[row0 + r0 + 3];
    size_t base = (size_t)(row0 + r0) * 128 + c4;
    ushort4 u;
    u.x = f2bf(a0.x * d0); u.y = f2bf(a0.y * d0); u.z = f2bf(a0.z * d0); u.w = f2bf(a0.w * d0);
    *(ushort4*)&hb[base] = u;
    u.x = f2bf(a1.x * d1); u.y = f2bf(a1.y * d1); u.z = f2bf(a1.z * d1); u.w = f2bf(a1.w * d1);
    *(ushort4*)&hb[base + 128] = u;
    u.x = f2bf(a2.x * d2); u.y = f2bf(a2.y * d2); u.z = f2bf(a2.z * d2); u.w = f2bf(a2.w * d2);
    *(ushort4*)&hb[base + 256] = u;
    u.x = f2bf(a3.x * d3); u.y = f2bf(a3.y * d3); u.z = f2bf(a3.z * d3); u.w = f2bf(a3.w * d3);
    *(ushort4*)&hb[base + 384] = u;
}

// gb'[row] = bf16( dis[row] * (ab @ W2)[row] ) ; ab = relu'd bf16 (32 rows/block)
__global__ __launch_bounds__(256) void k_gemm2(const uint* __restrict__ ab,
                                               const float* __restrict__ W2,
                                               const float* __restrict__ dis,
                                               ushort* __restrict__ gb) {
    __shared__ float wsh[128 * 64];    // 32 KB
    __shared__ float xs[32 * 132];     // padded stride 132
    const int t = threadIdx.x;
    {
        const float4* Wv = (const float4*)W2;
        float4* Sv = (float4*)wsh;
#pragma unroll
        for (int i = 0; i < 8; ++i) Sv[i * 256 + t] = Wv[i * 256 + t];
    }
    const int row0 = blockIdx.x * 32;
    {
        const uint4* Xv = (const uint4*)(ab + (size_t)row0 * 64);  // 8 bf16 per uint4
#pragma unroll
        for (int i = 0; i < 2; ++i) {
            int f = i * 256 + t;               // uint4 index; flat elem = f*8
            uint4 vv = Xv[f];
            int row = f >> 4, col = (f & 15) * 8;
            float* d = &xs[row * 132 + col];
            d[0] = bf2f(vv.x & 0xffffu); d[1] = bf2f(vv.x >> 16);
            d[2] = bf2f(vv.y & 0xffffu); d[3] = bf2f(vv.y >> 16);
            d[4] = bf2f(vv.z & 0xffffu); d[5] = bf2f(vv.z >> 16);
            d[6] = bf2f(vv.w & 0xffffu); d[7] = bf2f(vv.w >> 16);
        }
    }
    __syncthreads();
    const int c4 = (t & 15) * 4;
    const int r0 = (t >> 4) * 2;
    float4 a0{0,0,0,0}, a1{0,0,0,0};
#pragma unroll 4
    for (int k = 0; k < 128; ++k) {
        float4 w = *(const float4*)&wsh[k * 64 + c4];
        float x0 = xs[(r0 + 0) * 132 + k];
        float x1 = xs[(r0 + 1) * 132 + k];
        a0.x = fmaf(x0, w.x, a0.x); a0.y = fmaf(x0, w.y, a0.y);
        a0.z = fmaf(x0, w.z, a0.z); a0.w = fmaf(x0, w.w, a0.w);
        a1.x = fmaf(x1, w.x, a1.x); a1.y = fmaf(x1, w.y, a1.y);
        a1.z = fmaf(x1, w.z, a1.z); a1.w = fmaf(x1, w.w, a1.w);
    }
    const float d0 = dis[row0 + r0], d1 = dis[row0 + r0 + 1];
    size_t base = (size_t)(row0 + r0) * 64 + c4;
    ushort4 u;
    u.x = f2bf(a0.x * d0); u.y = f2bf(a0.y * d0); u.z = f2bf(a0.z * d0); u.w = f2bf(a0.w * d0);
    *(ushort4*)&gb[base] = u;
    u.x = f2bf(a1.x * d1); u.y = f2bf(a1.y * d1); u.z = f2bf(a1.z * d1); u.w = f2bf(a1.w * d1);
    *(ushort4*)&gb[base + 64] = u;
}

// ---- CSR aggregation: dim-chunked, XCD-L2-resident gathers ----
// chunk = blockIdx.x & 7 -> under round-robin block->XCD dispatch, each XCD
// works on one 16-dim (agg1) / 8-dim (agg2) slice: 3.2 MB / 1.6 MB, L2-fits.
// Wave layout agg1: 8 edge-slots x 8 lanes (1 uint = 2 dims per lane).

__global__ __launch_bounds__(256) void k_agg1(const int* __restrict__ rowptr,
                                              const int* __restrict__ ssrc,
                                              const float* __restrict__ dis,
                                              const uint* __restrict__ hbu,
                                              const float* __restrict__ b1,
                                              uint* __restrict__ abu) {
    const int t = threadIdx.x;
    const int wave = t >> 6;
    const int lane = t & 63;
    const int slot = lane >> 3;          // 0..7 edge slot
    const int d = lane & 7;              // uint within chunk
    const int chunk = blockIdx.x & 7;
    const int base = chunk * 8 + d;      // uint offset in 64-uint row
    const int ngroups = gridDim.x >> 3;
    for (int group = blockIdx.x >> 3; group < NGRP; group += ngroups) {
        const int v = group * 4 + wave;
        float ax = 0.f, ay = 0.f;
        const int end = rowptr[v + 1];
        for (int e = rowptr[v]; e < end; e += 8) {
            int idx = e + slot;
            if (idx < end) {
                int s = ssrc[idx];
                uint p = hbu[(size_t)s * 64 + base];
                ax += bf2f(p & 0xffffu);
                ay += bf2f(p >> 16);
            }
        }
        ax += __shfl_xor(ax, 8);  ay += __shfl_xor(ay, 8);
        ax += __shfl_xor(ax, 16); ay += __shfl_xor(ay, 16);
        ax += __shfl_xor(ax, 32); ay += __shfl_xor(ay, 32);
        if (slot == 0) {
            uint pv = hbu[(size_t)v * 64 + base];
            float tx = ax + bf2f(pv & 0xffffu);
            float ty = ay + bf2f(pv >> 16);
            const float dv = dis[v];
            const float2 bb = ((const float2*)b1)[base];
            float ox = fmaxf(fmaf(dv, tx, bb.x), 0.f);
            float oy = fmaxf(fmaf(dv, ty, bb.y), 0.f);
            abu[(size_t)v * 64 + base] = ((uint)f2bf(oy) << 16) | (uint)f2bf(ox);
        }
    }
}

// agg2: 16 edge-slots x 4 lanes (1 uint = 2 dims per lane), 8-dim chunks
__global__ __launch_bounds__(256) void k_agg2(const int* __restrict__ rowptr,
                                              const int* __restrict__ ssrc,
                                              const float* __restrict__ dis,
                                              const uint* __restrict__ gbu,
                                              const float* __restrict__ b2,
                                              float* __restrict__ out) {
    const int t = threadIdx.x;
    const int wave = t >> 6;
    const int lane = t & 63;
    const int slot = lane >> 2;          // 0..15 edge slot
    const int d = lane & 3;              // uint within chunk
    const int chunk = blockIdx.x & 7;
    const int base = chunk * 4 + d;      // uint offset in 32-uint row
    const int ngroups = gridDim.x >> 3;
    for (int group = blockIdx.x >> 3; group < NGRP; group += ngroups) {
        const int v = group * 4 + wave;
        float ax = 0.f, ay = 0.f;
        const int end = rowptr[v + 1];
        for (int e = rowptr[v]; e < end; e += 16) {
            int idx = e + slot;
            if (idx < end) {
                int s = ssrc[idx];
                uint p = gbu[(size_t)s * 32 + base];
                ax += bf2f(p & 0xffffu);
                ay += bf2f(p >> 16);
            }
        }
        ax += __shfl_xor(ax, 4);  ay += __shfl_xor(ay, 4);
        ax += __shfl_xor(ax, 8);  ay += __shfl_xor(ay, 8);
        ax += __shfl_xor(ax, 16); ay += __shfl_xor(ay, 16);
        ax += __shfl_xor(ax, 32); ay += __shfl_xor(ay, 32);
        if (slot == 0) {
            uint pv = gbu[(size_t)v * 32 + base];
            float tx = ax + bf2f(pv & 0xffffu);
            float ty = ay + bf2f(pv >> 16);
            const float dv = dis[v];
            const float2 bb = ((const float2*)b2)[base];
            float2 o;
            o.x = fmaf(dv, tx, bb.x);
            o.y = fmaf(dv, ty, bb.y);
            ((float2*)out)[(size_t)v * 32 + base] = o;
        }
    }
}

// ---------------- launch ----------------

extern "C" void kernel_launch(void* const* d_in, const int* in_sizes, int n_in,
                              void* d_out, int out_size, void* d_ws, size_t ws_size,
                              hipStream_t stream) {
    const float* x  = (const float*)d_in[0];
    const float* W1 = (const float*)d_in[1];
    const float* b1 = (const float*)d_in[2];
    const float* W2 = (const float*)d_in[3];
    const float* b2 = (const float*)d_in[4];
    const int*   ei = (const int*)d_in[5];
    const int* src = ei;
    const int* dst = ei + EDGES;
    float* out = (float*)d_out;

    char* w = (char*)d_ws;
    int*    hist   = (int*)w;    w += (size_t)NCH * NBUCK * 4 + 256;  // pad
    int*    bstart = (int*)w;    w += 256 * 4;
    int*    rowptr = (int*)w;    w += 100004 * 4;
    float*  dis    = (float*)w;  w += 100000 * 4 + 16;
    uint*   binned = (uint*)w;   w += (size_t)EDGES * 4;
    int*    ssrc   = (int*)w;    w += (size_t)EDGES * 4;
    ushort* hb     = (ushort*)w; w += (size_t)NODES * 128 * 2;
    uint*   ab     = (uint*)w;   w += (size_t)NODES * 64 * 4;
    ushort* gb     = (ushort*)w; w += (size_t)NODES * 64 * 2;

    k_hist   <<<NCH, 256, 0, stream>>>(dst, hist);
    k_offsets<<<1, 256, 0, stream>>>(hist, bstart, rowptr);
    k_bin    <<<NCH, 256, 0, stream>>>(src, dst, hist, binned);
    k_build  <<<NBUCK, 256, 0, stream>>>(binned, bstart, rowptr, dis, ssrc);

    k_gemm1  <<<NODES / 32, 256, 0, stream>>>(x, W1, dis, hb);
    k_agg1   <<<16384, 256, 0, stream>>>(rowptr, ssrc, dis, (const uint*)hb, b1, (uint*)ab);
    k_gemm2  <<<NODES / 32, 256, 0, stream>>>((const uint*)ab, W2, dis, gb);
    k_agg2   <<<16384, 256, 0, stream>>>(rowptr, ssrc, dis, (const uint*)gb, b2, out);
}

// Round 11
// 330.379 us; speedup vs baseline: 2.2152x; 2.2152x over previous
//
#include <hip/hip_runtime.h>

#define NODES 100000
#define EDGES 1600000
#define CHUNK 8192
#define NCH 196          // ceil(EDGES / CHUNK)
#define BSH 9            // bucket = dst >> 9  (512 nodes per bucket)
#define NBUCK 196        // ceil(NODES / 512)

typedef unsigned int uint;
typedef unsigned short ushort;
typedef __attribute__((ext_vector_type(8))) short bf16x8;
typedef __attribute__((ext_vector_type(4))) float f32x4;

__device__ __forceinline__ float bf2f(uint u) {
    union { uint i; float f; } c; c.i = u << 16; return c.f;
}
__device__ __forceinline__ ushort f2bf(float f) {
    union { float f; uint i; } c; c.f = f;
    uint r = c.i + 0x7fff + ((c.i >> 16) & 1);   // round-to-nearest-even
    return (ushort)(r >> 16);
}

// ---------------- preprocessing: LDS-binned counting sort by dst ----------------

__global__ __launch_bounds__(256) void k_hist(const int* __restrict__ dst,
                                              int* __restrict__ hist) {
    __shared__ int h[NBUCK];
    const int t = threadIdx.x;
    if (t < NBUCK) h[t] = 0;
    __syncthreads();
    const int base = blockIdx.x * CHUNK;
    const int len = min(CHUNK, EDGES - base);
    for (int i = t; i < len; i += 256)
        atomicAdd(&h[dst[base + i] >> BSH], 1);
    __syncthreads();
    if (t < NBUCK) hist[t * NCH + blockIdx.x] = h[t];   // bucket-major (transposed)
}

// per-bucket rows are contiguous -> each thread scans its own row serially
__global__ void k_offsets(int* __restrict__ hist, int* __restrict__ bucketStart,
                          int* __restrict__ rowptr) {
    __shared__ int sh[256];
    const int t = threadIdx.x;
    int run = 0;
    if (t < NBUCK) {
        int* rowp = hist + (size_t)t * NCH;
        for (int blk = 0; blk < NCH; ++blk) {
            int c = rowp[blk]; rowp[blk] = run; run += c;
        }
    }
    int v = (t < NBUCK) ? run : 0;
    sh[t] = v; __syncthreads();
    for (int off = 1; off < 256; off <<= 1) {
        int add = (t >= off) ? sh[t - off] : 0;
        __syncthreads(); sh[t] += add; __syncthreads();
    }
    int excl = sh[t] - v;
    if (t < NBUCK) {
        bucketStart[t] = excl;
        int* rowp = hist + (size_t)t * NCH;
        for (int blk = 0; blk < NCH; ++blk) rowp[blk] += excl;
    }
    if (t == 255) { bucketStart[NBUCK] = sh[255]; rowptr[NODES] = sh[255]; }
}

__global__ __launch_bounds__(256) void k_bin(const int* __restrict__ src,
                                             const int* __restrict__ dst,
                                             const int* __restrict__ hist,
                                             uint* __restrict__ binned) {
    __shared__ int curs[NBUCK];
    const int t = threadIdx.x;
    if (t < NBUCK) curs[t] = hist[t * NCH + blockIdx.x];
    __syncthreads();
    const int base = blockIdx.x * CHUNK;
    const int len = min(CHUNK, EDGES - base);
    for (int i = t; i < len; i += 256) {
        int d = dst[base + i];
        int s = src[base + i];
        int pos = atomicAdd(&curs[d >> BSH], 1);
        binned[pos] = ((uint)(d & 511) << 17) | (uint)s;
    }
}

__global__ __launch_bounds__(256) void k_build(const uint* __restrict__ binned,
                                               const int* __restrict__ bucketStart,
                                               int* __restrict__ rowptr,
                                               float* __restrict__ dis,
                                               int* __restrict__ ssrc) {
    __shared__ int cnt[512];
    __shared__ int sh[256];
    const int t = threadIdx.x;
    const int b = blockIdx.x;
    const int eBase = bucketStart[b], eEnd = bucketStart[b + 1];
    const int nodeBase = b << BSH;
    const int nnode = min(512, NODES - nodeBase);
    cnt[t * 2] = 0; cnt[t * 2 + 1] = 0;
    __syncthreads();
    for (int i = eBase + t; i < eEnd; i += 256)
        atomicAdd(&cnt[binned[i] >> 17], 1);
    __syncthreads();
    const int c0 = cnt[t * 2], c1 = cnt[t * 2 + 1];
    const int sum = c0 + c1;
    sh[t] = sum; __syncthreads();
    for (int off = 1; off < 256; off <<= 1) {
        int add = (t >= off) ? sh[t - off] : 0;
        __syncthreads(); sh[t] += add; __syncthreads();
    }
    int excl = sh[t] - sum;
    const int ln0 = t * 2;
    if (ln0 < nnode) {
        rowptr[nodeBase + ln0] = eBase + excl;
        dis[nodeBase + ln0] = rsqrtf((float)(1 + c0));
    }
    int excl1 = excl + c0;
    if (ln0 + 1 < nnode) {
        rowptr[nodeBase + ln0 + 1] = eBase + excl1;
        dis[nodeBase + ln0 + 1] = rsqrtf((float)(1 + c1));
    }
    cnt[ln0] = excl; cnt[ln0 + 1] = excl1;
    __syncthreads();
    for (int i = eBase + t; i < eEnd; i += 256) {
        uint p = binned[i];
        int pos = atomicAdd(&cnt[p >> 17], 1);
        ssrc[eBase + pos] = (int)(p & 0x1FFFFu);
    }
}

// ---------------- weight prep: transpose + bf16 (once per call) ----------------

__global__ void k_prepW(const float* __restrict__ W1, const float* __restrict__ W2,
                        ushort* __restrict__ W1t, ushort* __restrict__ W2t) {
    const int t = threadIdx.x + blockIdx.x * 256;
    for (int i = t; i < 128 * 128; i += 512) {
        int n = i >> 7, k = i & 127;
        W1t[i] = f2bf(W1[k * 128 + n]);   // W1t[n][k] = W1[k][n]
    }
    for (int i = t; i < 64 * 128; i += 512) {
        int n = i >> 7, k = i & 127;
        W2t[i] = f2bf(W2[k * 64 + n]);    // W2t[n][k] = W2[k][n]
    }
}

// ---------------- MFMA GEMMs (bf16 in, f32 acc, dis-scaled bf16 out) ----------

// hb'[row] = bf16( dis[row] * (x @ W1)[row] ) ; 64 rows/block, 4 waves x 16 rows
__global__ __launch_bounds__(256) void k_gemm1(const float* __restrict__ x,
                                               const ushort* __restrict__ W1t,
                                               const float* __restrict__ dis,
                                               ushort* __restrict__ hb) {
    __shared__ __align__(16) ushort wt[128 * 136];  // W1t rows, stride 136
    __shared__ __align__(16) ushort xs[64 * 136];   // x rows bf16, stride 136
    const int t = threadIdx.x;
    const int wave = t >> 6;
    const int lane = t & 63;
    const int row0 = blockIdx.x * 64;
    {   // stage W1t: 2048 uint4
        const uint4* Wg = (const uint4*)W1t;
#pragma unroll
        for (int i = 0; i < 8; ++i) {
            int flat = i * 256 + t;
            int n = flat >> 4, c = flat & 15;
            *(uint4*)&wt[n * 136 + c * 8] = Wg[flat];
        }
    }
    {   // stage x -> bf16: 4096 col-pairs
#pragma unroll
        for (int i = 0; i < 16; ++i) {
            int flat = i * 256 + t;
            int r = flat >> 6, cp = flat & 63;
            int row = row0 + r; if (row >= NODES) row = NODES - 1;
            float2 v = *(const float2*)&x[(size_t)row * 128 + cp * 2];
            *(uint*)&xs[r * 136 + cp * 2] = ((uint)f2bf(v.y) << 16) | (uint)f2bf(v.x);
        }
    }
    __syncthreads();
    const int arow = lane & 15;
    const int kg = (lane >> 4) * 8;
    f32x4 acc[8] = {};
#pragma unroll
    for (int ks = 0; ks < 4; ++ks) {
        const int k0 = ks * 32;
        bf16x8 a = *(const bf16x8*)&xs[(wave * 16 + arow) * 136 + k0 + kg];
#pragma unroll
        for (int nt = 0; nt < 8; ++nt) {
            bf16x8 b = *(const bf16x8*)&wt[(nt * 16 + arow) * 136 + k0 + kg];
            acc[nt] = __builtin_amdgcn_mfma_f32_16x16x32_bf16(a, b, acc[nt], 0, 0, 0);
        }
    }
    // epilogue: D[m][n]: m = 4*(lane>>4)+r, n = nt*16 + (lane&15)
    const int m4 = (lane >> 4) * 4;
    int nodes[4]; float dv[4];
#pragma unroll
    for (int r = 0; r < 4; ++r) {
        int node = row0 + wave * 16 + m4 + r;
        nodes[r] = node;
        dv[r] = dis[node < NODES ? node : NODES - 1];
    }
#pragma unroll
    for (int nt = 0; nt < 8; ++nt) {
#pragma unroll
        for (int r = 0; r < 4; ++r) {
            if (nodes[r] < NODES)
                hb[(size_t)nodes[r] * 128 + nt * 16 + (lane & 15)] = f2bf(acc[nt][r] * dv[r]);
        }
    }
}

// gb'[row] = bf16( dis[row] * (ab @ W2)[row] ) ; ab already bf16 (relu'd)
__global__ __launch_bounds__(256) void k_gemm2(const uint* __restrict__ ab,
                                               const ushort* __restrict__ W2t,
                                               const float* __restrict__ dis,
                                               ushort* __restrict__ gb) {
    __shared__ __align__(16) ushort wt[64 * 136];
    __shared__ __align__(16) ushort xs[64 * 136];
    const int t = threadIdx.x;
    const int wave = t >> 6;
    const int lane = t & 63;
    const int row0 = blockIdx.x * 64;
    {   // stage W2t: 64 rows x 128 k = 1024 uint4  (R10 BUG: staged only 512)
        const uint4* Wg = (const uint4*)W2t;
#pragma unroll
        for (int i = 0; i < 4; ++i) {
            int flat = i * 256 + t;
            int n = flat >> 4, c = flat & 15;
            *(uint4*)&wt[n * 136 + c * 8] = Wg[flat];
        }
    }
    {   // stage ab rows: 1024 uint4
        const uint4* Ag = (const uint4*)ab;
#pragma unroll
        for (int i = 0; i < 4; ++i) {
            int flat = i * 256 + t;
            int r = flat >> 4, c = flat & 15;
            int row = row0 + r; if (row >= NODES) row = NODES - 1;
            *(uint4*)&xs[r * 136 + c * 8] = Ag[(size_t)row * 16 + c];
        }
    }
    __syncthreads();
    const int arow = lane & 15;
    const int kg = (lane >> 4) * 8;
    f32x4 acc[4] = {};
#pragma unroll
    for (int ks = 0; ks < 4; ++ks) {
        const int k0 = ks * 32;
        bf16x8 a = *(const bf16x8*)&xs[(wave * 16 + arow) * 136 + k0 + kg];
#pragma unroll
        for (int nt = 0; nt < 4; ++nt) {
            bf16x8 b = *(const bf16x8*)&wt[(nt * 16 + arow) * 136 + k0 + kg];
            acc[nt] = __builtin_amdgcn_mfma_f32_16x16x32_bf16(a, b, acc[nt], 0, 0, 0);
        }
    }
    const int m4 = (lane >> 4) * 4;
    int nodes[4]; float dv[4];
#pragma unroll
    for (int r = 0; r < 4; ++r) {
        int node = row0 + wave * 16 + m4 + r;
        nodes[r] = node;
        dv[r] = dis[node < NODES ? node : NODES - 1];
    }
#pragma unroll
    for (int nt = 0; nt < 4; ++nt) {
#pragma unroll
        for (int r = 0; r < 4; ++r) {
            if (nodes[r] < NODES)
                gb[(size_t)nodes[r] * 64 + nt * 16 + (lane & 15)] = f2bf(acc[nt][r] * dv[r]);
        }
    }
}

// ---- CSR aggregation: 2 nodes/wave (one per 32-lane half), 4-edge unroll ----

__global__ void k_agg1(const int* __restrict__ rowptr, const int* __restrict__ ssrc,
                       const float* __restrict__ dis, const uint2* __restrict__ hb2,
                       const float* __restrict__ b1, uint2* __restrict__ ab2) {
    const int t = threadIdx.x;
    const int lane = t & 63;
    const int q = lane & 31;
    const int v = blockIdx.x * 8 + ((t >> 6) << 1) + (lane >> 5);
    float4 accA, accB = {0.f, 0.f, 0.f, 0.f};
    {
        uint2 pv = hb2[(size_t)v * 32 + q];
        accA.x = bf2f(pv.x & 0xffffu); accA.y = bf2f(pv.x >> 16);
        accA.z = bf2f(pv.y & 0xffffu); accA.w = bf2f(pv.y >> 16);
    }
    int e = rowptr[v];
    const int end = rowptr[v + 1];
    while (e < end) {
        int m = end - e; if (m > 32) m = 32;
        int s = (q < m) ? ssrc[e + q] : 0;
        int i = 0;
        for (; i + 4 <= m; i += 4) {
            int s0 = __shfl(s, i + 0, 32);
            int s1 = __shfl(s, i + 1, 32);
            int s2 = __shfl(s, i + 2, 32);
            int s3 = __shfl(s, i + 3, 32);
            uint2 p0 = hb2[(size_t)s0 * 32 + q];
            uint2 p1 = hb2[(size_t)s1 * 32 + q];
            uint2 p2 = hb2[(size_t)s2 * 32 + q];
            uint2 p3 = hb2[(size_t)s3 * 32 + q];
            accA.x += bf2f(p0.x & 0xffffu); accA.y += bf2f(p0.x >> 16);
            accA.z += bf2f(p0.y & 0xffffu); accA.w += bf2f(p0.y >> 16);
            accB.x += bf2f(p1.x & 0xffffu); accB.y += bf2f(p1.x >> 16);
            accB.z += bf2f(p1.y & 0xffffu); accB.w += bf2f(p1.y >> 16);
            accA.x += bf2f(p2.x & 0xffffu); accA.y += bf2f(p2.x >> 16);
            accA.z += bf2f(p2.y & 0xffffu); accA.w += bf2f(p2.y >> 16);
            accB.x += bf2f(p3.x & 0xffffu); accB.y += bf2f(p3.x >> 16);
            accB.z += bf2f(p3.y & 0xffffu); accB.w += bf2f(p3.y >> 16);
        }
        for (; i < m; ++i) {
            int s0 = __shfl(s, i, 32);
            uint2 p0 = hb2[(size_t)s0 * 32 + q];
            accA.x += bf2f(p0.x & 0xffffu); accA.y += bf2f(p0.x >> 16);
            accA.z += bf2f(p0.y & 0xffffu); accA.w += bf2f(p0.y >> 16);
        }
        e += m;
    }
    const float dv = dis[v];
    const float4 bb = ((const float4*)b1)[q];
    float ox = fmaxf(fmaf(dv, accA.x + accB.x, bb.x), 0.f);
    float oy = fmaxf(fmaf(dv, accA.y + accB.y, bb.y), 0.f);
    float oz = fmaxf(fmaf(dv, accA.z + accB.z, bb.z), 0.f);
    float ow = fmaxf(fmaf(dv, accA.w + accB.w, bb.w), 0.f);
    uint2 o;
    o.x = ((uint)f2bf(oy) << 16) | (uint)f2bf(ox);
    o.y = ((uint)f2bf(ow) << 16) | (uint)f2bf(oz);
    ab2[(size_t)v * 32 + q] = o;
}

__global__ void k_agg2(const int* __restrict__ rowptr, const int* __restrict__ ssrc,
                       const float* __restrict__ dis, const uint* __restrict__ gbu,
                       const float* __restrict__ b2, float* __restrict__ out) {
    const int t = threadIdx.x;
    const int lane = t & 63;
    const int q = lane & 31;
    const int v = blockIdx.x * 8 + ((t >> 6) << 1) + (lane >> 5);
    float2 accA, accB = {0.f, 0.f};
    {
        uint pv = gbu[(size_t)v * 32 + q];
        accA.x = bf2f(pv & 0xffffu); accA.y = bf2f(pv >> 16);
    }
    int e = rowptr[v];
    const int end = rowptr[v + 1];
    while (e < end) {
        int m = end - e; if (m > 32) m = 32;
        int s = (q < m) ? ssrc[e + q] : 0;
        int i = 0;
        for (; i + 4 <= m; i += 4) {
            int s0 = __shfl(s, i + 0, 32);
            int s1 = __shfl(s, i + 1, 32);
            int s2 = __shfl(s, i + 2, 32);
            int s3 = __shfl(s, i + 3, 32);
            uint p0 = gbu[(size_t)s0 * 32 + q];
            uint p1 = gbu[(size_t)s1 * 32 + q];
            uint p2 = gbu[(size_t)s2 * 32 + q];
            uint p3 = gbu[(size_t)s3 * 32 + q];
            accA.x += bf2f(p0 & 0xffffu); accA.y += bf2f(p0 >> 16);
            accB.x += bf2f(p1 & 0xffffu); accB.y += bf2f(p1 >> 16);
            accA.x += bf2f(p2 & 0xffffu); accA.y += bf2f(p2 >> 16);
            accB.x += bf2f(p3 & 0xffffu); accB.y += bf2f(p3 >> 16);
        }
        for (; i < m; ++i) {
            int s0 = __shfl(s, i, 32);
            uint p0 = gbu[(size_t)s0 * 32 + q];
            accA.x += bf2f(p0 & 0xffffu); accA.y += bf2f(p0 >> 16);
        }
        e += m;
    }
    const float dv = dis[v];
    const float2 bb = ((const float2*)b2)[q];
    float2 o;
    o.x = fmaf(dv, accA.x + accB.x, bb.x);
    o.y = fmaf(dv, accA.y + accB.y, bb.y);
    ((float2*)out)[(size_t)v * 32 + q] = o;
}

// ---------------- launch ----------------

extern "C" void kernel_launch(void* const* d_in, const int* in_sizes, int n_in,
                              void* d_out, int out_size, void* d_ws, size_t ws_size,
                              hipStream_t stream) {
    const float* x  = (const float*)d_in[0];
    const float* W1 = (const float*)d_in[1];
    const float* b1 = (const float*)d_in[2];
    const float* W2 = (const float*)d_in[3];
    const float* b2 = (const float*)d_in[4];
    const int*   ei = (const int*)d_in[5];
    const int* src = ei;
    const int* dst = ei + EDGES;
    float* out = (float*)d_out;

    char* w = (char*)d_ws;
    int*    hist   = (int*)w;    w += (size_t)NCH * NBUCK * 4 + 256;  // pad
    int*    bstart = (int*)w;    w += 256 * 4;
    int*    rowptr = (int*)w;    w += 100004 * 4;
    float*  dis    = (float*)w;  w += 100000 * 4 + 16;
    uint*   binned = (uint*)w;   w += (size_t)EDGES * 4;
    int*    ssrc   = (int*)w;    w += (size_t)EDGES * 4;
    ushort* hb     = (ushort*)w; w += (size_t)NODES * 128 * 2;
    uint*   ab     = (uint*)w;   w += (size_t)NODES * 64 * 4;
    ushort* gb     = (ushort*)w; w += (size_t)NODES * 64 * 2;
    ushort* W1t    = (ushort*)w; w += 128 * 128 * 2;
    ushort* W2t    = (ushort*)w; w += 64 * 128 * 2;

    k_prepW  <<<2, 256, 0, stream>>>(W1, W2, W1t, W2t);
    k_hist   <<<NCH, 256, 0, stream>>>(dst, hist);
    k_offsets<<<1, 256, 0, stream>>>(hist, bstart, rowptr);
    k_bin    <<<NCH, 256, 0, stream>>>(src, dst, hist, binned);
    k_build  <<<NBUCK, 256, 0, stream>>>(binned, bstart, rowptr, dis, ssrc);

    k_gemm1  <<<(NODES + 63) / 64, 256, 0, stream>>>(x, W1t, dis, hb);
    k_agg1   <<<NODES / 8, 256, 0, stream>>>(rowptr, ssrc, dis, (const uint2*)hb, b1, (uint2*)ab);
    k_gemm2  <<<(NODES + 63) / 64, 256, 0, stream>>>((const uint*)ab, W2t, dis, gb);
    k_agg2   <<<NODES / 8, 256, 0, stream>>>(rowptr, ssrc, dis, (const uint*)gb, b2, out);
}